// Round 8
// baseline (5816.685 us; speedup 1.0000x reference)
//
#include <hip/hip_runtime.h>
#include <math.h>

#define BB 128
#define NN 256
#define HH 512
#define T_STEPS 32
#define NBLK 256

__device__ __forceinline__ float fast_tanh(float x) {
    float e = __expf(2.0f * x);
    return 1.0f - 2.0f / (1.0f + e);
}
__device__ __forceinline__ float fast_sigmoid(float x) {
    return 1.0f / (1.0f + __expf(-x));
}

// ---------------- W1e = enc @ W1^T (32768x512x512 fp32, LDS-tiled, swizzled)
#define SW(j, i) ((i) ^ ((((j) >> 2) & 7) << 2))
__global__ __launch_bounds__(256) void w1e_gemm(const float* __restrict__ enc,
                                                const float* __restrict__ W1,
                                                float* __restrict__ W1e) {
    __shared__ float As[32][64];
    __shared__ float Bs[32][64];
    int tid = threadIdx.x;
    int i0 = blockIdx.x * 64;
    int k0 = blockIdx.y * 64;
    int tx = tid & 15, ty = tid >> 4;
    int srow = tid >> 3, sq = tid & 7;

    float acc[4][4];
#pragma unroll
    for (int a = 0; a < 4; a++)
#pragma unroll
        for (int c = 0; c < 4; c++) acc[a][c] = 0.f;

    for (int j0 = 0; j0 < HH; j0 += 32) {
#pragma unroll
        for (int p = 0; p < 2; p++) {
            int row = p * 32 + srow;
            float4 av = *(const float4*)(enc + (size_t)(i0 + row) * HH + j0 + sq * 4);
            float4 bv = *(const float4*)(W1 + (size_t)(k0 + row) * HH + j0 + sq * 4);
#pragma unroll
            for (int c = 0; c < 4; c++) {
                int j = sq * 4 + c;
                float va = (c == 0) ? av.x : (c == 1) ? av.y : (c == 2) ? av.z : av.w;
                float vb = (c == 0) ? bv.x : (c == 1) ? bv.y : (c == 2) ? bv.z : bv.w;
                As[j][SW(j, row)] = va;
                Bs[j][SW(j, row)] = vb;
            }
        }
        __syncthreads();
#pragma unroll
        for (int j = 0; j < 32; j++) {
            float4 a = *(const float4*)&As[j][SW(j, tx * 4)];
            float4 b = *(const float4*)&Bs[j][SW(j, ty * 4)];
            float ar[4] = {a.x, a.y, a.z, a.w};
            float br[4] = {b.x, b.y, b.z, b.w};
#pragma unroll
            for (int ai = 0; ai < 4; ai++)
#pragma unroll
                for (int bk = 0; bk < 4; bk++)
                    acc[ai][bk] += ar[ai] * br[bk];
        }
        __syncthreads();
    }
#pragma unroll
    for (int ai = 0; ai < 4; ai++) {
        float4 r = make_float4(acc[ai][0], acc[ai][1], acc[ai][2], acc[ai][3]);
        *(float4*)(W1e + (size_t)(i0 + tx * 4 + ai) * HH + k0 + ty * 4) = r;
    }
}

__global__ void init_kernel(float* __restrict__ hB0, float* __restrict__ xB,
                            int* __restrict__ arrive, int* __restrict__ pairflag) {
    int tid = blockIdx.x * blockDim.x + threadIdx.x;
    int nt = gridDim.x * blockDim.x;
    for (int i = tid; i < BB * HH; i += nt) { hB0[i] = 0.f; xB[i] = 0.f; }
    if (tid < NBLK) { arrive[tid] = 0; pairflag[tid] = 0; }
}

// distributed epoch barrier: store own slot (no RMW), poll all slots in parallel
__device__ __forceinline__ void gbar(int* arrive, int ep) {
    __syncthreads();
    int tid = threadIdx.x;
    if (tid == 0) {
        __threadfence();
        __hip_atomic_store(&arrive[blockIdx.x], ep, __ATOMIC_RELEASE,
                           __HIP_MEMORY_SCOPE_AGENT);
    }
    if (tid < NBLK) {
        while (__hip_atomic_load(&arrive[tid], __ATOMIC_RELAXED,
                                 __HIP_MEMORY_SCOPE_AGENT) < ep) {}
        __threadfence();
    }
    __syncthreads();
}

// weight-stationary k-partitioned decoder: 256 blocks x 1024 threads.
// block owns k0=blk*2 (GRU+W2 weights LDS-resident all 32 steps).
// score role: (sb=blk&127, hf=blk>>7) — pair partner = blk^128.
__global__ __launch_bounds__(1024) void decode_kernel(
    const float* __restrict__ enc,
    const float* __restrict__ w_ih, const float* __restrict__ w_hh,
    const float* __restrict__ b_ih, const float* __restrict__ b_hh,
    const float* __restrict__ W2, const float* __restrict__ v,
    const float* __restrict__ W1e,
    float* __restrict__ hB0, float* __restrict__ hB1,
    float* __restrict__ xB, float* __restrict__ W2hg,
    float* __restrict__ statsG, int* __restrict__ arrive,
    int* __restrict__ pairflag, float* __restrict__ out) {
    __shared__ float wl[12 * HH];   // 24KB GRU weights rows r=s*6+g6
    __shared__ float wl2[2 * HH];   // 4KB  W2 rows k0,k0+1
    __shared__ float scr[1536];     // 6KB  partials / u-scores
    __shared__ float redv[12];
    __shared__ int redi[4];
    __shared__ int mask_l[128];
    __shared__ float s_hm;
    __shared__ int s_idx;

    int blk = blockIdx.x, tid = threadIdx.x;
    int k0 = blk * 2;
    int sb = blk & 127, hf = blk >> 7;

    for (int u = tid; u < 12 * HH; u += 1024) {
        int r = u >> 9, j = u & 511;
        int s = r / 6, g6 = r % 6;
        int gg = (g6 < 3) ? g6 : g6 - 3;
        const float* src = (g6 < 3) ? w_ih : w_hh;
        wl[u] = src[(size_t)(gg * HH + k0 + s) * HH + j];
    }
    for (int u = tid; u < 2 * HH; u += 1024)
        wl2[u] = W2[(size_t)(k0 + (u >> 9)) * HH + (u & 511)];
    if (tid < 128) mask_l[tid] = 0;
    __syncthreads();

    int lane = tid & 63, wv = tid >> 6;
    int b4 = tid >> 5, jh = tid & 31;

    float vr[8];
    {
        const float* vp = v + lane * 8;
        float4 va = *(const float4*)vp;
        float4 vb = *(const float4*)(vp + 4);
        vr[0] = va.x; vr[1] = va.y; vr[2] = va.z; vr[3] = va.w;
        vr[4] = vb.x; vr[5] = vb.y; vr[6] = vb.z; vr[7] = vb.w;
    }

    for (int t = 0; t < T_STEPS; t++) {
        const float* hBc = (t & 1) ? hB1 : hB0;
        float* hBn = (t & 1) ? hB0 : hB1;

        // ---- A: GRU partials (lane-parallel j, coalesced x/h, butterfly reduce)
        {
            float acc[12][4];
#pragma unroll
            for (int r = 0; r < 12; r++)
#pragma unroll
                for (int bi = 0; bi < 4; bi++) acc[r][bi] = 0.f;
            const float* xr0 = xB + (size_t)(b4 * 4) * HH;
            const float* xr1 = xr0 + HH;
            const float* xr2 = xr1 + HH;
            const float* xr3 = xr2 + HH;
            const float* hr0 = hBc + (size_t)(b4 * 4) * HH;
            const float* hr1 = hr0 + HH;
            const float* hr2 = hr1 + HH;
            const float* hr3 = hr2 + HH;
            for (int jj = 0; jj < 16; jj++) {
                int j = (jj << 5) | jh;
                float xv0 = xr0[j], xv1 = xr1[j], xv2 = xr2[j], xv3 = xr3[j];
                float hv0 = hr0[j], hv1 = hr1[j], hv2 = hr2[j], hv3 = hr3[j];
#pragma unroll
                for (int r = 0; r < 12; r++) {
                    float w = wl[r * HH + j];
                    if ((r % 6) < 3) {
                        acc[r][0] += xv0 * w; acc[r][1] += xv1 * w;
                        acc[r][2] += xv2 * w; acc[r][3] += xv3 * w;
                    } else {
                        acc[r][0] += hv0 * w; acc[r][1] += hv1 * w;
                        acc[r][2] += hv2 * w; acc[r][3] += hv3 * w;
                    }
                }
            }
#pragma unroll
            for (int m = 1; m <= 16; m <<= 1)
#pragma unroll
                for (int r = 0; r < 12; r++)
#pragma unroll
                    for (int bi = 0; bi < 4; bi++)
                        acc[r][bi] += __shfl_xor(acc[r][bi], m);
            if (jh == 0) {
#pragma unroll
                for (int r = 0; r < 12; r++)
#pragma unroll
                    for (int bi = 0; bi < 4; bi++)
                        scr[b4 * 48 + r * 4 + bi] = acc[r][bi];
            }
        }
        __syncthreads();
        if (tid < 256) {
            int ss = tid >> 7, bb = tid & 127;
            int k = k0 + ss;
            const float* g = scr + (bb >> 2) * 48 + ss * 24 + (bb & 3);
            float ir = g[0], iz = g[4], inn = g[8];
            float hrv = g[12], hzv = g[16], hnv = g[20];
            float r = fast_sigmoid(ir + b_ih[k] + hrv + b_hh[k]);
            float z = fast_sigmoid(iz + b_ih[HH + k] + hzv + b_hh[HH + k]);
            float n = fast_tanh(inn + b_ih[2 * HH + k] + r * (hnv + b_hh[2 * HH + k]));
            float hold = hBc[(size_t)bb * HH + k];
            hBn[(size_t)bb * HH + k] = (1.f - z) * n + z * hold;
        }
        gbar(arrive, t * 3 + 1);

        // ---- B: W2h (same access pattern)
        {
            float a0 = 0, a1 = 0, a2 = 0, a3 = 0, c0 = 0, c1 = 0, c2 = 0, c3 = 0;
            const float* h0p = hBn + (size_t)(b4 * 4) * HH;
            const float* h1p = h0p + HH;
            const float* h2p = h1p + HH;
            const float* h3p = h2p + HH;
            for (int jj = 0; jj < 16; jj++) {
                int j = (jj << 5) | jh;
                float hv0 = h0p[j], hv1 = h1p[j], hv2 = h2p[j], hv3 = h3p[j];
                float w0 = wl2[j], w1 = wl2[HH + j];
                a0 += hv0 * w0; a1 += hv1 * w0; a2 += hv2 * w0; a3 += hv3 * w0;
                c0 += hv0 * w1; c1 += hv1 * w1; c2 += hv2 * w1; c3 += hv3 * w1;
            }
#pragma unroll
            for (int m = 1; m <= 16; m <<= 1) {
                a0 += __shfl_xor(a0, m); a1 += __shfl_xor(a1, m);
                a2 += __shfl_xor(a2, m); a3 += __shfl_xor(a3, m);
                c0 += __shfl_xor(c0, m); c1 += __shfl_xor(c1, m);
                c2 += __shfl_xor(c2, m); c3 += __shfl_xor(c3, m);
            }
            if (jh == 0) {
                float* p = scr + b4 * 8;
                p[0] = a0; p[1] = a1; p[2] = a2; p[3] = a3;
                p[4] = c0; p[5] = c1; p[6] = c2; p[7] = c3;
            }
        }
        __syncthreads();
        if (tid < 256) {
            int ss = tid >> 7, bb = tid & 127;
            W2hg[(size_t)bb * HH + k0 + ss] = scr[(bb >> 2) * 8 + ss * 4 + (bb & 3)];
        }
        gbar(arrive, t * 3 + 2);

        // ---- C: score (wave per n, lane-major k)
        {
            float w2r[8];
            const float* wp = W2hg + (size_t)sb * HH + lane * 8;
            float4 wa = *(const float4*)wp;
            float4 wb = *(const float4*)(wp + 4);
            w2r[0] = wa.x; w2r[1] = wa.y; w2r[2] = wa.z; w2r[3] = wa.w;
            w2r[4] = wb.x; w2r[5] = wb.y; w2r[6] = wb.z; w2r[7] = wb.w;
            const float* Wbase = W1e + ((size_t)sb * NN + hf * 128) * HH;
#pragma unroll 2
            for (int nn = 0; nn < 8; nn++) {
                int nl = wv * 8 + nn;
                const float* Wp = Wbase + (size_t)nl * HH + lane * 8;
                float4 A0 = *(const float4*)Wp;
                float4 A1 = *(const float4*)(Wp + 4);
                float p = fast_tanh(A0.x + w2r[0]) * vr[0] +
                          fast_tanh(A0.y + w2r[1]) * vr[1] +
                          fast_tanh(A0.z + w2r[2]) * vr[2] +
                          fast_tanh(A0.w + w2r[3]) * vr[3] +
                          fast_tanh(A1.x + w2r[4]) * vr[4] +
                          fast_tanh(A1.y + w2r[5]) * vr[5] +
                          fast_tanh(A1.z + w2r[6]) * vr[6] +
                          fast_tanh(A1.w + w2r[7]) * vr[7];
                p += __shfl_xor(p, 1);
                p += __shfl_xor(p, 2);
                p += __shfl_xor(p, 4);
                p += __shfl_xor(p, 8);
                p += __shfl_xor(p, 16);
                p += __shfl_xor(p, 32);
                if (lane == 0) scr[nl] = p;
            }
        }
        __syncthreads();
        float val = -3.0e38f;
        if (tid < 128) {
            val = mask_l[tid] ? -1.0e9f : scr[tid];
            float bv = val;
            int bi = hf * 128 + tid;
            for (int off = 32; off > 0; off >>= 1) {
                float ov = __shfl_down(bv, off);
                int oi = __shfl_down(bi, off);
                if (ov > bv || (ov == bv && oi < bi)) { bv = ov; bi = oi; }
            }
            if ((tid & 63) == 0) { redv[tid >> 6] = bv; redi[tid >> 6] = bi; }
        }
        __syncthreads();
        if (tid == 0) {
            if (redv[1] > redv[0]) { s_hm = redv[1]; redi[2] = redi[1]; }
            else { s_hm = redv[0]; redi[2] = redi[0]; }
        }
        __syncthreads();
        if (tid < 128) {
            float d = val - s_hm;
            float e = expf(d);
            float ed = e * d;
            for (int off = 32; off > 0; off >>= 1) {
                e += __shfl_down(e, off);
                ed += __shfl_down(ed, off);
            }
            if ((tid & 63) == 0) { redv[4 + (tid >> 6)] = e; redv[8 + (tid >> 6)] = ed; }
        }
        __syncthreads();
        if (tid == 0) {
            float m = s_hm, S = redv[4] + redv[5], E = redv[8] + redv[9];
            float* sp = statsG + ((size_t)sb * 2 + hf) * 4;
            sp[0] = m; sp[1] = S; sp[2] = E; sp[3] = (float)redi[2];
            __threadfence();
            __hip_atomic_store(&pairflag[blk], t + 1, __ATOMIC_RELEASE,
                               __HIP_MEMORY_SCOPE_AGENT);
            int partner = blk ^ 128;
            while (__hip_atomic_load(&pairflag[partner], __ATOMIC_RELAXED,
                                     __HIP_MEMORY_SCOPE_AGENT) < t + 1) {}
            __threadfence();
            const float* s0 = statsG + ((size_t)sb * 2 + 0) * 4;
            const float* s1 = statsG + ((size_t)sb * 2 + 1) * 4;
            float m0 = s0[0], S0 = s0[1], E0 = s0[2]; int i0 = (int)s0[3];
            float m1 = s1[0], S1 = s1[1], E1 = s1[2]; int i1 = (int)s1[3];
            float mm; int idx;
            if (m1 > m0) { mm = m1; idx = i1; } else { mm = m0; idx = i0; }
            float cc0 = expf(m0 - mm), cc1 = expf(m1 - mm);
            float Sc = S0 * cc0 + S1 * cc1;
            float Ec = (E0 + (m0 - mm) * S0) * cc0 + (E1 + (m1 - mm) * S1) * cc1;
            s_idx = idx;
            if (hf == 0) {
                float inv = 1.0f / Sc;
                out[sb * T_STEPS + t] = (float)idx;
                out[BB * T_STEPS + sb * T_STEPS + t] = logf(inv + 1e-9f);
                out[2 * BB * T_STEPS + sb * T_STEPS + t] = logf(Sc) - inv * Ec;
            }
        }
        __syncthreads();
        {
            int idx = s_idx;
            if (tid < 256) {
                int j = hf * 256 + tid;
                xB[(size_t)sb * HH + j] = enc[((size_t)sb * NN + idx) * HH + j];
            }
            if (tid == 0 && (idx >> 7) == hf) mask_l[idx & 127] = 1;
        }
        gbar(arrive, t * 3 + 3);
    }
}

extern "C" void kernel_launch(void* const* d_in, const int* in_sizes, int n_in,
                              void* d_out, int out_size, void* d_ws, size_t ws_size,
                              hipStream_t stream) {
    const float* enc  = (const float*)d_in[0];
    const float* w_ih = (const float*)d_in[1];
    const float* w_hh = (const float*)d_in[2];
    const float* b_ih = (const float*)d_in[3];
    const float* b_hh = (const float*)d_in[4];
    const float* W1   = (const float*)d_in[5];
    const float* W2   = (const float*)d_in[6];
    const float* v    = (const float*)d_in[7];
    float* out = (float*)d_out;

    float* ws = (float*)d_ws;
    float* W1e    = ws;                             // 16777216 floats (64MB)
    float* hB0    = W1e + (size_t)BB * NN * HH;     // 65536
    float* hB1    = hB0 + (size_t)BB * HH;          // 65536
    float* xB     = hB1 + (size_t)BB * HH;          // 65536
    float* W2hg   = xB + (size_t)BB * HH;           // 65536
    float* statsG = W2hg + (size_t)BB * HH;         // 1024
    int*   arrive   = (int*)(statsG + 1024);        // 256
    int*   pairflag = arrive + NBLK;                // 256

    init_kernel<<<64, 256, 0, stream>>>(hB0, xB, arrive, pairflag);
    w1e_gemm<<<dim3((BB * NN) / 64, HH / 64), 256, 0, stream>>>(enc, W1, W1e);

    void* args[] = {
        (void*)&enc, (void*)&w_ih, (void*)&w_hh, (void*)&b_ih, (void*)&b_hh,
        (void*)&W2, (void*)&v, (void*)&W1e, (void*)&hB0, (void*)&hB1,
        (void*)&xB, (void*)&W2hg, (void*)&statsG, (void*)&arrive,
        (void*)&pairflag, (void*)&out};
    hipLaunchCooperativeKernel((void*)decode_kernel, dim3(NBLK), dim3(1024),
                               args, 0, stream);
}

// Round 9
// 5408.936 us; speedup vs baseline: 1.0754x; 1.0754x over previous
//
#include <hip/hip_runtime.h>
#include <math.h>

#define BB 128
#define NN 256
#define HH 512
#define T_STEPS 32
#define NBLK 256

__device__ __forceinline__ float fast_tanh(float x) {
    float e = __expf(2.0f * x);
    return 1.0f - 2.0f / (1.0f + e);
}
__device__ __forceinline__ float fast_sigmoid(float x) {
    return 1.0f / (1.0f + __expf(-x));
}

// ---------------- W1e = enc @ W1^T (32768x512x512 fp32, LDS-tiled, swizzled)
#define SW(j, i) ((i) ^ ((((j) >> 2) & 7) << 2))
__global__ __launch_bounds__(256) void w1e_gemm(const float* __restrict__ enc,
                                                const float* __restrict__ W1,
                                                float* __restrict__ W1e) {
    __shared__ float As[32][64];
    __shared__ float Bs[32][64];
    int tid = threadIdx.x;
    int i0 = blockIdx.x * 64;
    int k0 = blockIdx.y * 64;
    int tx = tid & 15, ty = tid >> 4;
    int srow = tid >> 3, sq = tid & 7;

    float acc[4][4];
#pragma unroll
    for (int a = 0; a < 4; a++)
#pragma unroll
        for (int c = 0; c < 4; c++) acc[a][c] = 0.f;

    for (int j0 = 0; j0 < HH; j0 += 32) {
#pragma unroll
        for (int p = 0; p < 2; p++) {
            int row = p * 32 + srow;
            float4 av = *(const float4*)(enc + (size_t)(i0 + row) * HH + j0 + sq * 4);
            float4 bv = *(const float4*)(W1 + (size_t)(k0 + row) * HH + j0 + sq * 4);
#pragma unroll
            for (int c = 0; c < 4; c++) {
                int j = sq * 4 + c;
                float va = (c == 0) ? av.x : (c == 1) ? av.y : (c == 2) ? av.z : av.w;
                float vb = (c == 0) ? bv.x : (c == 1) ? bv.y : (c == 2) ? bv.z : bv.w;
                As[j][SW(j, row)] = va;
                Bs[j][SW(j, row)] = vb;
            }
        }
        __syncthreads();
#pragma unroll
        for (int j = 0; j < 32; j++) {
            float4 a = *(const float4*)&As[j][SW(j, tx * 4)];
            float4 b = *(const float4*)&Bs[j][SW(j, ty * 4)];
            float ar[4] = {a.x, a.y, a.z, a.w};
            float br[4] = {b.x, b.y, b.z, b.w};
#pragma unroll
            for (int ai = 0; ai < 4; ai++)
#pragma unroll
                for (int bk = 0; bk < 4; bk++)
                    acc[ai][bk] += ar[ai] * br[bk];
        }
        __syncthreads();
    }
#pragma unroll
    for (int ai = 0; ai < 4; ai++) {
        float4 r = make_float4(acc[ai][0], acc[ai][1], acc[ai][2], acc[ai][3]);
        *(float4*)(W1e + (size_t)(i0 + tx * 4 + ai) * HH + k0 + ty * 4) = r;
    }
}

__global__ void init_kernel(float* __restrict__ hT0, float* __restrict__ xB,
                            int* __restrict__ arrive, int* __restrict__ pairflag) {
    int tid = blockIdx.x * blockDim.x + threadIdx.x;
    int nt = gridDim.x * blockDim.x;
    for (int i = tid; i < BB * HH; i += nt) { hT0[i] = 0.f; xB[i] = 0.f; }
    if (tid < NBLK) { arrive[tid] = 0; pairflag[tid] = 0; }
}

// distributed epoch barrier: store own slot (no RMW), poll all slots in parallel
__device__ __forceinline__ void gbar(int* arrive, int ep) {
    __syncthreads();
    int tid = threadIdx.x;
    if (tid == 0) {
        __threadfence();
        __hip_atomic_store(&arrive[blockIdx.x], ep, __ATOMIC_RELEASE,
                           __HIP_MEMORY_SCOPE_AGENT);
    }
    if (tid < NBLK) {
        while (__hip_atomic_load(&arrive[tid], __ATOMIC_RELAXED,
                                 __HIP_MEMORY_SCOPE_AGENT) < ep) {}
        __threadfence();
    }
    __syncthreads();
}

// weight-stationary k-partitioned decoder, coherent-layout edition.
// hT/W2hT transposed [k][b] (owner writes full lines); xB row-major [b][j].
__global__ __launch_bounds__(1024) void decode_kernel(
    const float* __restrict__ enc,
    const float* __restrict__ w_ih, const float* __restrict__ w_hh,
    const float* __restrict__ b_ih, const float* __restrict__ b_hh,
    const float* __restrict__ W2, const float* __restrict__ v,
    const float* __restrict__ W1e,
    float* __restrict__ hT0, float* __restrict__ hT1,
    float* __restrict__ xB, float* __restrict__ W2hT,
    float* __restrict__ statsG, int* __restrict__ arrive,
    int* __restrict__ pairflag, float* __restrict__ out) {
    __shared__ float wlh[6 * HH];       // 12KB h-gate weights rows d=s*3+g
    __shared__ float wl2[2 * HH];       // 4KB W2 rows k0,k0+1
    __shared__ float w2l[HH];           // 2KB gathered W2h row
    __shared__ float scrA[128 * 49];    // 25KB x-partials [b][u<8][6] pad49
    __shared__ float scrH[8 * 128 * 6]; // 24KB h-partials [sub][b][6]
    __shared__ float scrB[8 * 128 * 2]; // 8KB W2h partials
    __shared__ float u_s[128];
    __shared__ float redv[12];
    __shared__ int redi[4];
    __shared__ int mask_l[128];
    __shared__ float s_hm;
    __shared__ int s_idx;

    int blk = blockIdx.x, tid = threadIdx.x;
    int k0 = blk * 2, sb = blk & 127, hf = blk >> 7;
    int lane = tid & 63, wv = tid >> 6;

    for (int u = tid; u < 6 * HH; u += 1024) {
        int d = u >> 9, j = u & 511;
        int s = d / 3, g = d % 3;
        wlh[u] = w_hh[(size_t)(g * HH + k0 + s) * HH + j];
    }
    for (int u = tid; u < 2 * HH; u += 1024)
        wl2[u] = W2[(size_t)(k0 + (u >> 9)) * HH + (u & 511)];
    if (tid < 128) mask_l[tid] = 0;

    // persistent registers: x-gate weights (48) + v (8)
    float wx[6][8];
#pragma unroll
    for (int d = 0; d < 6; d++) {
        int s = d / 3, g = d % 3;
        const float* p = w_ih + (size_t)(g * HH + k0 + s) * HH + lane * 8;
        float4 A = *(const float4*)p;
        float4 B4 = *(const float4*)(p + 4);
        wx[d][0] = A.x; wx[d][1] = A.y; wx[d][2] = A.z; wx[d][3] = A.w;
        wx[d][4] = B4.x; wx[d][5] = B4.y; wx[d][6] = B4.z; wx[d][7] = B4.w;
    }
    float vr[8];
    {
        const float* p = v + lane * 8;
        float4 A = *(const float4*)p;
        float4 B4 = *(const float4*)(p + 4);
        vr[0] = A.x; vr[1] = A.y; vr[2] = A.z; vr[3] = A.w;
        vr[4] = B4.x; vr[5] = B4.y; vr[6] = B4.z; vr[7] = B4.w;
    }
    __syncthreads();

    for (int t = 0; t < T_STEPS; t++) {
        const float* hc = (t & 1) ? hT1 : hT0;
        float* hn_ = (t & 1) ? hT0 : hT1;

        // ---- A-x: wave per 8 rows, lanes span j, weights in registers
        if (t > 0) {
            int bw = wv << 3;
            for (int i = 0; i < 8; i++) {
                int b = bw + i;
                const float* xp = xB + (size_t)b * HH + lane * 8;
                float4 xa = *(const float4*)xp;
                float4 xb4 = *(const float4*)(xp + 4);
                float xr[8] = {xa.x, xa.y, xa.z, xa.w, xb4.x, xb4.y, xb4.z, xb4.w};
                float acc[6];
#pragma unroll
                for (int d = 0; d < 6; d++) {
                    float a = 0.f;
#pragma unroll
                    for (int c = 0; c < 8; c++) a += wx[d][c] * xr[c];
                    acc[d] = a;
                }
#pragma unroll
                for (int m = 1; m <= 4; m <<= 1)
#pragma unroll
                    for (int d = 0; d < 6; d++)
                        acc[d] += __shfl_xor(acc[d], m);
                if ((lane & 7) == 0) {
                    float* p = &scrA[b * 49 + (lane >> 3) * 6];
#pragma unroll
                    for (int d = 0; d < 6; d++) p[d] = acc[d];
                }
            }
        }
        // ---- A-h: lanes span b, LDS-broadcast weights, coalesced hT rows
        {
            int sub = tid >> 7, b = tid & 127;
            int jb = sub * 64;
            float acc6[6] = {0.f, 0.f, 0.f, 0.f, 0.f, 0.f};
            for (int q = 0; q < 16; q++) {
                int j = jb + q * 4;
                float h0 = hc[(j + 0) * BB + b];
                float h1 = hc[(j + 1) * BB + b];
                float h2 = hc[(j + 2) * BB + b];
                float h3 = hc[(j + 3) * BB + b];
#pragma unroll
                for (int d = 0; d < 6; d++) {
                    float4 w = *(const float4*)&wlh[d * HH + j];
                    acc6[d] += w.x * h0 + w.y * h1 + w.z * h2 + w.w * h3;
                }
            }
            float* p = &scrH[(sub * 128 + b) * 6];
#pragma unroll
            for (int d = 0; d < 6; d++) p[d] = acc6[d];
        }
        __syncthreads();
        // ---- gate combine: write hT_next rows (full lines)
        if (tid < 256) {
            int s = tid >> 7, b = tid & 127;
            int k = k0 + s, d0 = s * 3;
            float xs0 = 0.f, xs1 = 0.f, xs2 = 0.f;
            if (t > 0) {
#pragma unroll
                for (int u = 0; u < 8; u++) {
                    const float* p = &scrA[b * 49 + u * 6 + d0];
                    xs0 += p[0]; xs1 += p[1]; xs2 += p[2];
                }
            }
            float hs0 = 0.f, hs1 = 0.f, hs2 = 0.f;
#pragma unroll
            for (int sub = 0; sub < 8; sub++) {
                const float* p = &scrH[(sub * 128 + b) * 6 + d0];
                hs0 += p[0]; hs1 += p[1]; hs2 += p[2];
            }
            float r = fast_sigmoid(xs0 + b_ih[k] + hs0 + b_hh[k]);
            float z = fast_sigmoid(xs1 + b_ih[HH + k] + hs1 + b_hh[HH + k]);
            float n = fast_tanh(xs2 + b_ih[2 * HH + k] + r * (hs2 + b_hh[2 * HH + k]));
            float hold = hc[k * BB + b];
            hn_[k * BB + b] = (1.f - z) * n + z * hold;
        }
        gbar(arrive, t * 3 + 1);

        // ---- B: W2h, same pattern, write W2hT rows (full lines)
        {
            int sub = tid >> 7, b = tid & 127;
            int jb = sub * 64;
            float a0 = 0.f, a1 = 0.f;
            for (int q = 0; q < 16; q++) {
                int j = jb + q * 4;
                float h0 = hn_[(j + 0) * BB + b];
                float h1 = hn_[(j + 1) * BB + b];
                float h2 = hn_[(j + 2) * BB + b];
                float h3 = hn_[(j + 3) * BB + b];
                float4 w0 = *(const float4*)&wl2[j];
                float4 w1 = *(const float4*)&wl2[HH + j];
                a0 += w0.x * h0 + w0.y * h1 + w0.z * h2 + w0.w * h3;
                a1 += w1.x * h0 + w1.y * h1 + w1.z * h2 + w1.w * h3;
            }
            float* p = &scrB[(sub * 128 + b) * 2];
            p[0] = a0; p[1] = a1;
        }
        __syncthreads();
        if (tid < 256) {
            int s = tid >> 7, b = tid & 127;
            float acc = 0.f;
#pragma unroll
            for (int sub = 0; sub < 8; sub++)
                acc += scrB[(sub * 128 + b) * 2 + s];
            W2hT[(size_t)(k0 + s) * BB + b] = acc;
        }
        gbar(arrive, t * 3 + 2);

        // ---- C: gather W2h row, score, stats, pair-combine, outputs, xB
        if (tid < HH) w2l[tid] = W2hT[(size_t)tid * BB + sb];
        __syncthreads();
        {
            float w2r[8];
            {
                const float* p = &w2l[lane * 8];
                float4 A = *(const float4*)p;
                float4 B4 = *(const float4*)(p + 4);
                w2r[0] = A.x; w2r[1] = A.y; w2r[2] = A.z; w2r[3] = A.w;
                w2r[4] = B4.x; w2r[5] = B4.y; w2r[6] = B4.z; w2r[7] = B4.w;
            }
            const float* Wbase = W1e + ((size_t)sb * NN + hf * 128) * HH;
#pragma unroll 2
            for (int nn = 0; nn < 8; nn++) {
                int nl = wv * 8 + nn;
                const float* Wp = Wbase + (size_t)nl * HH + lane * 8;
                float4 A0 = *(const float4*)Wp;
                float4 A1 = *(const float4*)(Wp + 4);
                float p = fast_tanh(A0.x + w2r[0]) * vr[0] +
                          fast_tanh(A0.y + w2r[1]) * vr[1] +
                          fast_tanh(A0.z + w2r[2]) * vr[2] +
                          fast_tanh(A0.w + w2r[3]) * vr[3] +
                          fast_tanh(A1.x + w2r[4]) * vr[4] +
                          fast_tanh(A1.y + w2r[5]) * vr[5] +
                          fast_tanh(A1.z + w2r[6]) * vr[6] +
                          fast_tanh(A1.w + w2r[7]) * vr[7];
                p += __shfl_xor(p, 1);
                p += __shfl_xor(p, 2);
                p += __shfl_xor(p, 4);
                p += __shfl_xor(p, 8);
                p += __shfl_xor(p, 16);
                p += __shfl_xor(p, 32);
                if (lane == 0) u_s[nl] = p;
            }
        }
        __syncthreads();
        float val = -3.0e38f;
        if (tid < 128) {
            val = mask_l[tid] ? -1.0e9f : u_s[tid];
            float bv = val;
            int bi = hf * 128 + tid;
            for (int off = 32; off > 0; off >>= 1) {
                float ov = __shfl_down(bv, off);
                int oi = __shfl_down(bi, off);
                if (ov > bv || (ov == bv && oi < bi)) { bv = ov; bi = oi; }
            }
            if ((tid & 63) == 0) { redv[tid >> 6] = bv; redi[tid >> 6] = bi; }
        }
        __syncthreads();
        if (tid == 0) {
            if (redv[1] > redv[0]) { s_hm = redv[1]; redi[2] = redi[1]; }
            else { s_hm = redv[0]; redi[2] = redi[0]; }
        }
        __syncthreads();
        if (tid < 128) {
            float d = val - s_hm;
            float e = expf(d);
            float ed = e * d;
            for (int off = 32; off > 0; off >>= 1) {
                e += __shfl_down(e, off);
                ed += __shfl_down(ed, off);
            }
            if ((tid & 63) == 0) { redv[4 + (tid >> 6)] = e; redv[8 + (tid >> 6)] = ed; }
        }
        __syncthreads();
        if (tid == 0) {
            float m = s_hm, S = redv[4] + redv[5], E = redv[8] + redv[9];
            float* sp = statsG + ((size_t)sb * 2 + hf) * 4;
            sp[0] = m; sp[1] = S; sp[2] = E; sp[3] = (float)redi[2];
            __threadfence();
            __hip_atomic_store(&pairflag[blk], t + 1, __ATOMIC_RELEASE,
                               __HIP_MEMORY_SCOPE_AGENT);
            int partner = blk ^ 128;
            while (__hip_atomic_load(&pairflag[partner], __ATOMIC_RELAXED,
                                     __HIP_MEMORY_SCOPE_AGENT) < t + 1) {}
            __threadfence();
            const float* s0 = statsG + ((size_t)sb * 2 + 0) * 4;
            const float* s1 = statsG + ((size_t)sb * 2 + 1) * 4;
            float m0 = s0[0], S0 = s0[1], E0 = s0[2]; int i0 = (int)s0[3];
            float m1 = s1[0], S1 = s1[1], E1 = s1[2]; int i1 = (int)s1[3];
            float mm; int idx;
            if (m1 > m0) { mm = m1; idx = i1; } else { mm = m0; idx = i0; }
            float cc0 = expf(m0 - mm), cc1 = expf(m1 - mm);
            float Sc = S0 * cc0 + S1 * cc1;
            float Ec = (E0 + (m0 - mm) * S0) * cc0 + (E1 + (m1 - mm) * S1) * cc1;
            s_idx = idx;
            if (hf == 0) {
                float inv = 1.0f / Sc;
                out[sb * T_STEPS + t] = (float)idx;
                out[BB * T_STEPS + sb * T_STEPS + t] = logf(inv + 1e-9f);
                out[2 * BB * T_STEPS + sb * T_STEPS + t] = logf(Sc) - inv * Ec;
            }
        }
        __syncthreads();
        {
            int idx = s_idx;
            if (tid < 256) {
                int j = hf * 256 + tid;
                xB[(size_t)sb * HH + j] = enc[((size_t)sb * NN + idx) * HH + j];
            }
            if (tid == 0 && (idx >> 7) == hf) mask_l[idx & 127] = 1;
        }
        gbar(arrive, t * 3 + 3);
    }
}

extern "C" void kernel_launch(void* const* d_in, const int* in_sizes, int n_in,
                              void* d_out, int out_size, void* d_ws, size_t ws_size,
                              hipStream_t stream) {
    const float* enc  = (const float*)d_in[0];
    const float* w_ih = (const float*)d_in[1];
    const float* w_hh = (const float*)d_in[2];
    const float* b_ih = (const float*)d_in[3];
    const float* b_hh = (const float*)d_in[4];
    const float* W1   = (const float*)d_in[5];
    const float* W2   = (const float*)d_in[6];
    const float* v    = (const float*)d_in[7];
    float* out = (float*)d_out;

    float* ws = (float*)d_ws;
    float* W1e    = ws;                             // 16777216 floats (64MB)
    float* hT0    = W1e + (size_t)BB * NN * HH;     // 65536
    float* hT1    = hT0 + (size_t)BB * HH;          // 65536
    float* xB     = hT1 + (size_t)BB * HH;          // 65536
    float* W2hT   = xB + (size_t)BB * HH;           // 65536
    float* statsG = W2hT + (size_t)BB * HH;         // 1024
    int*   arrive   = (int*)(statsG + 1024);        // 256
    int*   pairflag = arrive + NBLK;                // 256

    init_kernel<<<64, 256, 0, stream>>>(hT0, xB, arrive, pairflag);
    w1e_gemm<<<dim3((BB * NN) / 64, HH / 64), 256, 0, stream>>>(enc, W1, W1e);

    void* args[] = {
        (void*)&enc, (void*)&w_ih, (void*)&w_hh, (void*)&b_ih, (void*)&b_hh,
        (void*)&W2, (void*)&v, (void*)&W1e, (void*)&hT0, (void*)&hT1,
        (void*)&xB, (void*)&W2hT, (void*)&statsG, (void*)&arrive,
        (void*)&pairflag, (void*)&out};
    hipLaunchCooperativeKernel((void*)decode_kernel, dim3(NBLK), dim3(1024),
                               args, 0, stream);
}

// Round 11
// 4000.593 us; speedup vs baseline: 1.4540x; 1.3520x over previous
//
#include <hip/hip_runtime.h>
#include <math.h>

#define BB 128
#define NN 256
#define HH 512
#define T_STEPS 32
#define JQ 128        // HH/4 j-quads
#define RB 2          // rows per decode block
#define DBLK (BB/RB)  // 64 decode blocks

__device__ __forceinline__ float fast_tanh(float x) {
    float e = __expf(2.0f * x);
    return 1.0f - 2.0f / (1.0f + e);
}
__device__ __forceinline__ float fast_sigmoid(float x) {
    return 1.0f / (1.0f + __expf(-x));
}

// ---------------- W1e = enc @ W1^T (32768x512x512 fp32, LDS-tiled, swizzled)
#define SW(j, i) ((i) ^ ((((j) >> 2) & 7) << 2))
__global__ __launch_bounds__(256) void w1e_gemm(const float* __restrict__ enc,
                                                const float* __restrict__ W1,
                                                float* __restrict__ W1e) {
    __shared__ float As[32][64];
    __shared__ float Bs[32][64];
    int tid = threadIdx.x;
    int i0 = blockIdx.x * 64;
    int k0 = blockIdx.y * 64;
    int tx = tid & 15, ty = tid >> 4;
    int srow = tid >> 3, sq = tid & 7;

    float acc[4][4];
#pragma unroll
    for (int a = 0; a < 4; a++)
#pragma unroll
        for (int c = 0; c < 4; c++) acc[a][c] = 0.f;

    for (int j0 = 0; j0 < HH; j0 += 32) {
#pragma unroll
        for (int p = 0; p < 2; p++) {
            int row = p * 32 + srow;
            float4 av = *(const float4*)(enc + (size_t)(i0 + row) * HH + j0 + sq * 4);
            float4 bv = *(const float4*)(W1 + (size_t)(k0 + row) * HH + j0 + sq * 4);
#pragma unroll
            for (int c = 0; c < 4; c++) {
                int j = sq * 4 + c;
                float va = (c == 0) ? av.x : (c == 1) ? av.y : (c == 2) ? av.z : av.w;
                float vb = (c == 0) ? bv.x : (c == 1) ? bv.y : (c == 2) ? bv.z : bv.w;
                As[j][SW(j, row)] = va;
                Bs[j][SW(j, row)] = vb;
            }
        }
        __syncthreads();
#pragma unroll
        for (int j = 0; j < 32; j++) {
            float4 a = *(const float4*)&As[j][SW(j, tx * 4)];
            float4 b = *(const float4*)&Bs[j][SW(j, ty * 4)];
            float ar[4] = {a.x, a.y, a.z, a.w};
            float br[4] = {b.x, b.y, b.z, b.w};
#pragma unroll
            for (int ai = 0; ai < 4; ai++)
#pragma unroll
                for (int bk = 0; bk < 4; bk++)
                    acc[ai][bk] += ar[ai] * br[bk];
        }
        __syncthreads();
    }
#pragma unroll
    for (int ai = 0; ai < 4; ai++) {
        float4 r = make_float4(acc[ai][0], acc[ai][1], acc[ai][2], acc[ai][3]);
        *(float4*)(W1e + (size_t)(i0 + tx * 4 + ai) * HH + k0 + ty * 4) = r;
    }
}

// ---------------- one-time weight transpose into lane-coalesced j-quad planes
// gT4[(g*JQ+jq)*HH + k]: g=0..2 -> w_ih gates r,z,n ; g=3..5 -> w_hh gates r,z,n
__global__ __launch_bounds__(512) void prep_kernel(const float* __restrict__ w_ih,
                                                   const float* __restrict__ w_hh,
                                                   const float* __restrict__ W2,
                                                   float4* __restrict__ gT4,
                                                   float4* __restrict__ w2T4) {
    int bid = blockIdx.x;
    int k = threadIdx.x;
    if (bid < 6 * JQ) {
        int g = bid / JQ, jq = bid % JQ;
        const float* src = (g < 3) ? w_ih : w_hh;
        const float* p = src + (size_t)((g % 3) * HH + k) * HH + jq * 4;
        gT4[(size_t)(g * JQ + jq) * HH + k] = make_float4(p[0], p[1], p[2], p[3]);
    } else {
        int jq = bid - 6 * JQ;
        const float* p = W2 + (size_t)k * HH + jq * 4;
        w2T4[(size_t)jq * HH + k] = make_float4(p[0], p[1], p[2], p[3]);
    }
}

#define PT(r, g, j, kk) part[((((r)*6 + (g)) * 2 + (j)) << 9) + (kk)]
#define WP(r, j, kk) part[((((r)*2 + (j))) << 9) + (kk)]

// ---------------- persistent decoder: RB=2 batch rows per block, no inter-block
// sync. Weight float4s fetched once feed both rows' FMAs (2x arithmetic
// intensity on the dominant gT4 stream).
__global__ __launch_bounds__(1024) void decode_kernel(
    const float* __restrict__ enc,
    const float* __restrict__ b_ih, const float* __restrict__ b_hh,
    const float4* __restrict__ gT4, const float4* __restrict__ w2T4,
    const float* __restrict__ v, const float* __restrict__ W1e,
    float* __restrict__ out) {
    __shared__ float x_l[RB][HH];
    __shared__ float h_l[RB][HH];
    __shared__ float w2l[RB][HH];
    __shared__ float part[RB * 6 * 2 * 512];   // 49KB GRU partials (aliased by W2h)
    __shared__ float ul[RB][NN];
    __shared__ int mask_l[RB][NN];
    __shared__ float redm[8];
    __shared__ int redi[8];
    __shared__ float redS[8], redE[8];
    __shared__ float s_m[RB];
    __shared__ int s_idx[RB];

    int blk = blockIdx.x, tid = threadIdx.x;
    int sb0 = blk * RB;
    int lane = tid & 63, wv = tid >> 6;
    int k = tid & 511, jh = tid >> 9;   // GRU/W2h role
    int jq0 = jh * 64;

    {
        int r = tid >> 9, j = tid & 511;
        x_l[r][j] = 0.f;
        h_l[r][j] = 0.f;
    }
    if (tid < 512) mask_l[tid >> 8][tid & 255] = 0;

    float vr[8];
    {
        const float* p = v + lane * 8;
        float4 A = *(const float4*)p;
        float4 B = *(const float4*)(p + 4);
        vr[0] = A.x; vr[1] = A.y; vr[2] = A.z; vr[3] = A.w;
        vr[4] = B.x; vr[5] = B.y; vr[6] = B.z; vr[7] = B.w;
    }
    __syncthreads();

    for (int t = 0; t < T_STEPS; t++) {
        // ---- GRU partials: thread (k, jh); 6 weight streams feed both rows
        {
            float a0 = 0, a1 = 0, a2 = 0, a3 = 0, a4 = 0, a5 = 0;
            float a6 = 0, a7 = 0, a8 = 0, a9 = 0, a10 = 0, a11 = 0;
#pragma unroll 2
            for (int jq = jq0; jq < jq0 + 64; jq++) {
                float4 x0 = *(const float4*)&x_l[0][jq * 4];
                float4 h0 = *(const float4*)&h_l[0][jq * 4];
                float4 x1 = *(const float4*)&x_l[1][jq * 4];
                float4 h1 = *(const float4*)&h_l[1][jq * 4];
                float4 w0 = gT4[(size_t)(0 * JQ + jq) * HH + k];
                float4 w1 = gT4[(size_t)(1 * JQ + jq) * HH + k];
                float4 w2 = gT4[(size_t)(2 * JQ + jq) * HH + k];
                float4 w3 = gT4[(size_t)(3 * JQ + jq) * HH + k];
                float4 w4 = gT4[(size_t)(4 * JQ + jq) * HH + k];
                float4 w5 = gT4[(size_t)(5 * JQ + jq) * HH + k];
                a0 += x0.x * w0.x + x0.y * w0.y + x0.z * w0.z + x0.w * w0.w;
                a1 += x0.x * w1.x + x0.y * w1.y + x0.z * w1.z + x0.w * w1.w;
                a2 += x0.x * w2.x + x0.y * w2.y + x0.z * w2.z + x0.w * w2.w;
                a3 += h0.x * w3.x + h0.y * w3.y + h0.z * w3.z + h0.w * w3.w;
                a4 += h0.x * w4.x + h0.y * w4.y + h0.z * w4.z + h0.w * w4.w;
                a5 += h0.x * w5.x + h0.y * w5.y + h0.z * w5.z + h0.w * w5.w;
                a6 += x1.x * w0.x + x1.y * w0.y + x1.z * w0.z + x1.w * w0.w;
                a7 += x1.x * w1.x + x1.y * w1.y + x1.z * w1.z + x1.w * w1.w;
                a8 += x1.x * w2.x + x1.y * w2.y + x1.z * w2.z + x1.w * w2.w;
                a9 += h1.x * w3.x + h1.y * w3.y + h1.z * w3.z + h1.w * w3.w;
                a10 += h1.x * w4.x + h1.y * w4.y + h1.z * w4.z + h1.w * w4.w;
                a11 += h1.x * w5.x + h1.y * w5.y + h1.z * w5.z + h1.w * w5.w;
            }
            PT(0, 0, jh, k) = a0;  PT(0, 1, jh, k) = a1;  PT(0, 2, jh, k) = a2;
            PT(0, 3, jh, k) = a3;  PT(0, 4, jh, k) = a4;  PT(0, 5, jh, k) = a5;
            PT(1, 0, jh, k) = a6;  PT(1, 1, jh, k) = a7;  PT(1, 2, jh, k) = a8;
            PT(1, 3, jh, k) = a9;  PT(1, 4, jh, k) = a10; PT(1, 5, jh, k) = a11;
        }
        __syncthreads();
        // ---- gate combine (1024 threads = 2 rows x 512 k)
        {
            int rw = tid >> 9, kk = tid & 511;
            float ir = PT(rw, 0, 0, kk) + PT(rw, 0, 1, kk);
            float iz = PT(rw, 1, 0, kk) + PT(rw, 1, 1, kk);
            float inn = PT(rw, 2, 0, kk) + PT(rw, 2, 1, kk);
            float hr = PT(rw, 3, 0, kk) + PT(rw, 3, 1, kk);
            float hz = PT(rw, 4, 0, kk) + PT(rw, 4, 1, kk);
            float hn = PT(rw, 5, 0, kk) + PT(rw, 5, 1, kk);
            float r = fast_sigmoid(ir + b_ih[kk] + hr + b_hh[kk]);
            float z = fast_sigmoid(iz + b_ih[HH + kk] + hz + b_hh[HH + kk]);
            float n = fast_tanh(inn + b_ih[2 * HH + kk] + r * (hn + b_hh[2 * HH + kk]));
            h_l[rw][kk] = (1.f - z) * n + z * h_l[rw][kk];
        }
        __syncthreads();

        // ---- W2h: one weight stream feeds both rows (aliases part[0..2047])
        {
            float b0 = 0.f, b1 = 0.f;
#pragma unroll 4
            for (int jq = jq0; jq < jq0 + 64; jq++) {
                float4 h0 = *(const float4*)&h_l[0][jq * 4];
                float4 h1 = *(const float4*)&h_l[1][jq * 4];
                float4 w = w2T4[(size_t)jq * HH + k];
                b0 += h0.x * w.x + h0.y * w.y + h0.z * w.z + h0.w * w.w;
                b1 += h1.x * w.x + h1.y * w.y + h1.z * w.z + h1.w * w.w;
            }
            WP(0, jh, k) = b0;
            WP(1, jh, k) = b1;
        }
        __syncthreads();
        {
            int rw = tid >> 9, kk = tid & 511;
            w2l[rw][kk] = WP(rw, 0, kk) + WP(rw, 1, kk);
        }
        __syncthreads();

        // ---- score: wave per n, lane-major k (coalesced W1e stream)
        {
            int row = wv >> 3, n0 = (wv & 7) * 32;
            float w2r[8];
            {
                const float* p = &w2l[row][lane * 8];
                float4 A = *(const float4*)p;
                float4 B = *(const float4*)(p + 4);
                w2r[0] = A.x; w2r[1] = A.y; w2r[2] = A.z; w2r[3] = A.w;
                w2r[4] = B.x; w2r[5] = B.y; w2r[6] = B.z; w2r[7] = B.w;
            }
            const float* Wb = W1e + (size_t)(sb0 + row) * NN * HH + lane * 8;
#pragma unroll 4
            for (int i = 0; i < 32; i++) {
                int n = n0 + i;
                const float* Wp = Wb + (size_t)n * HH;
                float4 A0 = *(const float4*)Wp;
                float4 A1 = *(const float4*)(Wp + 4);
                float p = fast_tanh(A0.x + w2r[0]) * vr[0] +
                          fast_tanh(A0.y + w2r[1]) * vr[1] +
                          fast_tanh(A0.z + w2r[2]) * vr[2] +
                          fast_tanh(A0.w + w2r[3]) * vr[3] +
                          fast_tanh(A1.x + w2r[4]) * vr[4] +
                          fast_tanh(A1.y + w2r[5]) * vr[5] +
                          fast_tanh(A1.z + w2r[6]) * vr[6] +
                          fast_tanh(A1.w + w2r[7]) * vr[7];
                p += __shfl_xor(p, 1);
                p += __shfl_xor(p, 2);
                p += __shfl_xor(p, 4);
                p += __shfl_xor(p, 8);
                p += __shfl_xor(p, 16);
                p += __shfl_xor(p, 32);
                if (lane == 0) ul[row][n] = p;
            }
        }
        __syncthreads();

        // ---- masked first-index argmax: waves 0-3 row0, waves 4-7 row1
        float val = -3.0e38f;
        int rrow = tid >> 8, nn = tid & 255;
        if (tid < 512) {
            val = mask_l[rrow][nn] ? -1.0e9f : ul[rrow][nn];
            float bv = val;
            int bi = nn;
            for (int off = 32; off > 0; off >>= 1) {
                float ov = __shfl_down(bv, off);
                int oi = __shfl_down(bi, off);
                if (ov > bv || (ov == bv && oi < bi)) { bv = ov; bi = oi; }
            }
            if (lane == 0) { redm[wv] = bv; redi[wv] = bi; }
        }
        __syncthreads();
        if (tid < 512 && nn == 0) {   // tid==0 (row0), tid==256 (row1)
            int base = rrow * 4;
            float m = redm[base]; int mi = redi[base];
#pragma unroll
            for (int w = 1; w < 4; w++) {
                if (redm[base + w] > m ||
                    (redm[base + w] == m && redi[base + w] < mi)) {
                    m = redm[base + w]; mi = redi[base + w];
                }
            }
            s_m[rrow] = m; s_idx[rrow] = mi;
        }
        __syncthreads();

        // ---- softmax denominator + entropy sum
        if (tid < 512) {
            float d = val - s_m[rrow];
            float e = __expf(d);
            float ed = e * d;
            for (int off = 32; off > 0; off >>= 1) {
                e += __shfl_down(e, off);
                ed += __shfl_down(ed, off);
            }
            if (lane == 0) { redS[wv] = e; redE[wv] = ed; }
        }
        __syncthreads();
        if (tid < 512 && nn == 0) {
            int base = rrow * 4;
            float S = redS[base] + redS[base + 1] + redS[base + 2] + redS[base + 3];
            float E = redE[base] + redE[base + 1] + redE[base + 2] + redE[base + 3];
            float inv = 1.0f / S;
            int sbr = sb0 + rrow;
            int idx = s_idx[rrow];
            out[sbr * T_STEPS + t] = (float)idx;
            out[BB * T_STEPS + sbr * T_STEPS + t] = logf(inv + 1e-9f);
            out[2 * BB * T_STEPS + sbr * T_STEPS + t] = logf(S) - inv * E;
            mask_l[rrow][idx] = 1;
        }
        __syncthreads();
        // ---- gather prev_embed for next step (both rows)
        {
            int r = tid >> 9, j = tid & 511;
            x_l[r][j] = enc[((size_t)(sb0 + r) * NN + s_idx[r]) * HH + j];
        }
        __syncthreads();
    }
}

extern "C" void kernel_launch(void* const* d_in, const int* in_sizes, int n_in,
                              void* d_out, int out_size, void* d_ws, size_t ws_size,
                              hipStream_t stream) {
    const float* enc  = (const float*)d_in[0];
    const float* w_ih = (const float*)d_in[1];
    const float* w_hh = (const float*)d_in[2];
    const float* b_ih = (const float*)d_in[3];
    const float* b_hh = (const float*)d_in[4];
    const float* W1   = (const float*)d_in[5];
    const float* W2   = (const float*)d_in[6];
    const float* v    = (const float*)d_in[7];
    float* out = (float*)d_out;

    float* ws = (float*)d_ws;
    float*  W1e  = ws;                                     // 16777216 floats (64MB)
    float4* gT4  = (float4*)(W1e + (size_t)BB * NN * HH);  // 393216 float4 (6MB)
    float4* w2T4 = gT4 + (size_t)6 * JQ * HH;              // 65536 float4 (1MB)

    w1e_gemm<<<dim3((BB * NN) / 64, HH / 64), 256, 0, stream>>>(enc, W1, W1e);
    prep_kernel<<<7 * JQ, 512, 0, stream>>>(w_ih, w_hh, W2, gT4, w2T4);
    decode_kernel<<<DBLK, 1024, 0, stream>>>(enc, b_ih, b_hh, gT4, w2T4, v,
                                             W1e, out);
}

// Round 12
// 2961.093 us; speedup vs baseline: 1.9644x; 1.3511x over previous
//
#include <hip/hip_runtime.h>
#include <math.h>

#define BB 128
#define NN 256
#define HH 512
#define T_STEPS 32
#define JQ 128
#define GQ 4
#define NBLK 256

__device__ __forceinline__ float fast_tanh(float x) {
    float e = __expf(2.0f * x);
    return 1.0f - 2.0f / (1.0f + e);
}
__device__ __forceinline__ float fast_sigmoid(float x) {
    return 1.0f / (1.0f + __expf(-x));
}

// ---------------- W1e = enc @ W1^T (32768x512x512 fp32, LDS-tiled, swizzled)
#define SW(j, i) ((i) ^ ((((j) >> 2) & 7) << 2))
__global__ __launch_bounds__(256) void w1e_gemm(const float* __restrict__ enc,
                                                const float* __restrict__ W1,
                                                float* __restrict__ W1e) {
    __shared__ float As[32][64];
    __shared__ float Bs[32][64];
    int tid = threadIdx.x;
    int i0 = blockIdx.x * 64;
    int k0 = blockIdx.y * 64;
    int tx = tid & 15, ty = tid >> 4;
    int srow = tid >> 3, sq = tid & 7;

    float acc[4][4];
#pragma unroll
    for (int a = 0; a < 4; a++)
#pragma unroll
        for (int c = 0; c < 4; c++) acc[a][c] = 0.f;

    for (int j0 = 0; j0 < HH; j0 += 32) {
#pragma unroll
        for (int p = 0; p < 2; p++) {
            int row = p * 32 + srow;
            float4 av = *(const float4*)(enc + (size_t)(i0 + row) * HH + j0 + sq * 4);
            float4 bv = *(const float4*)(W1 + (size_t)(k0 + row) * HH + j0 + sq * 4);
#pragma unroll
            for (int c = 0; c < 4; c++) {
                int j = sq * 4 + c;
                float va = (c == 0) ? av.x : (c == 1) ? av.y : (c == 2) ? av.z : av.w;
                float vb = (c == 0) ? bv.x : (c == 1) ? bv.y : (c == 2) ? bv.z : bv.w;
                As[j][SW(j, row)] = va;
                Bs[j][SW(j, row)] = vb;
            }
        }
        __syncthreads();
#pragma unroll
        for (int j = 0; j < 32; j++) {
            float4 a = *(const float4*)&As[j][SW(j, tx * 4)];
            float4 b = *(const float4*)&Bs[j][SW(j, ty * 4)];
            float ar[4] = {a.x, a.y, a.z, a.w};
            float br[4] = {b.x, b.y, b.z, b.w};
#pragma unroll
            for (int ai = 0; ai < 4; ai++)
#pragma unroll
                for (int bk = 0; bk < 4; bk++)
                    acc[ai][bk] += ar[ai] * br[bk];
        }
        __syncthreads();
    }
#pragma unroll
    for (int ai = 0; ai < 4; ai++) {
        float4 r = make_float4(acc[ai][0], acc[ai][1], acc[ai][2], acc[ai][3]);
        *(float4*)(W1e + (size_t)(i0 + tx * 4 + ai) * HH + k0 + ty * 4) = r;
    }
}

// ---------------- one-time weight transpose into lane-coalesced j-quad planes
__global__ __launch_bounds__(512) void prep_kernel(const float* __restrict__ w_ih,
                                                   const float* __restrict__ w_hh,
                                                   const float* __restrict__ W2,
                                                   float4* __restrict__ gT4,
                                                   float4* __restrict__ w2T4) {
    int bid = blockIdx.x;
    int k = threadIdx.x;
    if (bid < 6 * JQ) {
        int g = bid / JQ, jq = bid % JQ;
        const float* src = (g < 3) ? w_ih : w_hh;
        const float* p = src + (size_t)((g % 3) * HH + k) * HH + jq * 4;
        gT4[(size_t)(g * JQ + jq) * HH + k] = make_float4(p[0], p[1], p[2], p[3]);
    } else {
        int jq = bid - 6 * JQ;
        const float* p = W2 + (size_t)k * HH + jq * 4;
        w2T4[(size_t)jq * HH + k] = make_float4(p[0], p[1], p[2], p[3]);
    }
}

__global__ void init_kernel(int* __restrict__ arr) {
    int tid = blockIdx.x * blockDim.x + threadIdx.x;
    if (tid < NBLK) arr[tid * 16] = 0;
}

// group-local epoch sync: store own padded slot, 4 threads poll group slots.
__device__ __forceinline__ void gsync(int* __restrict__ arr, int g, int blk,
                                      int tid, int ep) {
    __syncthreads();
    if (tid == 0) {
        __threadfence();
        __hip_atomic_store(&arr[blk * 16], ep, __ATOMIC_RELEASE,
                           __HIP_MEMORY_SCOPE_AGENT);
    }
    if (tid < GQ) {
        while (__hip_atomic_load(&arr[(g * GQ + tid) * 16], __ATOMIC_RELAXED,
                                 __HIP_MEMORY_SCOPE_AGENT) < ep) {}
        __threadfence();
    }
    __syncthreads();
}

// ---------------- quad-group decoder: group = 4 blocks = 2 rows, j-quartered.
// h/x stay block-local (k-quarter == j-quarter). 3 group syncs/step.
__global__ __launch_bounds__(1024) void decode_kernel(
    const float* __restrict__ enc,
    const float* __restrict__ b_ih, const float* __restrict__ b_hh,
    const float4* __restrict__ gT4, const float4* __restrict__ w2T4,
    const float* __restrict__ v, const float* __restrict__ W1e,
    float* __restrict__ exg, float* __restrict__ exg2,
    float* __restrict__ statsX, int* __restrict__ arr,
    float* __restrict__ out) {
    __shared__ float part[2][6][2][512];   // 48KB GRU partials [r][gate][jh][k]
    __shared__ float wp[2][2][512];        // 8KB W2h partials
    __shared__ float x_l[2][128];          // own j-quarter of x
    __shared__ float h_l[2][128];          // own j-quarter of h
    __shared__ float w2l[2][512];          // full W2h, both rows
    __shared__ float ul[2][64];            // own n-quarter scores
    __shared__ int mask_l[2][NN];
    __shared__ int s_idx[2];

    int blk = blockIdx.x, tid = threadIdx.x;
    int g = blk >> 2, q = blk & 3;
    int lane = tid & 63, wv = tid >> 6;
    int k9 = tid & 511, jh = tid >> 9;

    if (tid < 256) { x_l[tid >> 7][tid & 127] = 0.f; h_l[tid >> 7][tid & 127] = 0.f; }
    if (tid < 512) mask_l[tid >> 8][tid & 255] = 0;

    float vr[8];
    {
        const float* p = v + lane * 8;
        float4 A = *(const float4*)p;
        float4 B = *(const float4*)(p + 4);
        vr[0] = A.x; vr[1] = A.y; vr[2] = A.z; vr[3] = A.w;
        vr[4] = B.x; vr[5] = B.y; vr[6] = B.z; vr[7] = B.w;
    }
    __syncthreads();

    const size_t exgB = (size_t)blk * 6144;
    const size_t exg2B = (size_t)blk * 1024;

    for (int t = 0; t < T_STEPS; t++) {
        // ---- GRU partials over own j-quarter (stream = 1.5MB gT4 quarter)
        {
            float a0 = 0, a1 = 0, a2 = 0, a3 = 0, a4 = 0, a5 = 0;
            float a6 = 0, a7 = 0, a8 = 0, a9 = 0, a10 = 0, a11 = 0;
            int jqbeg = q * 32 + jh * 16;
#pragma unroll 2
            for (int jj = 0; jj < 16; jj++) {
                int jq = jqbeg + jj;
                int jl4 = (jq - q * 32) * 4;
                float4 x0 = *(const float4*)&x_l[0][jl4];
                float4 h0 = *(const float4*)&h_l[0][jl4];
                float4 x1 = *(const float4*)&x_l[1][jl4];
                float4 h1 = *(const float4*)&h_l[1][jl4];
                float4 w0 = gT4[(size_t)(0 * JQ + jq) * HH + k9];
                float4 w1 = gT4[(size_t)(1 * JQ + jq) * HH + k9];
                float4 w2 = gT4[(size_t)(2 * JQ + jq) * HH + k9];
                float4 w3 = gT4[(size_t)(3 * JQ + jq) * HH + k9];
                float4 w4 = gT4[(size_t)(4 * JQ + jq) * HH + k9];
                float4 w5 = gT4[(size_t)(5 * JQ + jq) * HH + k9];
                a0 += x0.x * w0.x + x0.y * w0.y + x0.z * w0.z + x0.w * w0.w;
                a1 += x0.x * w1.x + x0.y * w1.y + x0.z * w1.z + x0.w * w1.w;
                a2 += x0.x * w2.x + x0.y * w2.y + x0.z * w2.z + x0.w * w2.w;
                a3 += h0.x * w3.x + h0.y * w3.y + h0.z * w3.z + h0.w * w3.w;
                a4 += h0.x * w4.x + h0.y * w4.y + h0.z * w4.z + h0.w * w4.w;
                a5 += h0.x * w5.x + h0.y * w5.y + h0.z * w5.z + h0.w * w5.w;
                a6 += x1.x * w0.x + x1.y * w0.y + x1.z * w0.z + x1.w * w0.w;
                a7 += x1.x * w1.x + x1.y * w1.y + x1.z * w1.z + x1.w * w1.w;
                a8 += x1.x * w2.x + x1.y * w2.y + x1.z * w2.z + x1.w * w2.w;
                a9 += h1.x * w3.x + h1.y * w3.y + h1.z * w3.z + h1.w * w3.w;
                a10 += h1.x * w4.x + h1.y * w4.y + h1.z * w4.z + h1.w * w4.w;
                a11 += h1.x * w5.x + h1.y * w5.y + h1.z * w5.z + h1.w * w5.w;
            }
            part[0][0][jh][k9] = a0;  part[0][1][jh][k9] = a1;
            part[0][2][jh][k9] = a2;  part[0][3][jh][k9] = a3;
            part[0][4][jh][k9] = a4;  part[0][5][jh][k9] = a5;
            part[1][0][jh][k9] = a6;  part[1][1][jh][k9] = a7;
            part[1][2][jh][k9] = a8;  part[1][3][jh][k9] = a9;
            part[1][4][jh][k9] = a10; part[1][5][jh][k9] = a11;
        }
        __syncthreads();
        // exchange write (jh-combined), coalesced
#pragma unroll
        for (int u = tid, it = 0; it < 6; it++, u += 1024) {
            int rg = u >> 9, kk = u & 511;
            int r = rg >= 6 ? 1 : 0, g6 = rg - r * 6;
            exg[exgB + u] = part[r][g6][0][kk] + part[r][g6][1][kk];
        }
        gsync(arr, g, blk, tid, 3 * t + 1);

        // ---- gate combine for own k-quarter; h stays local
        if (tid < 256) {
            int r = tid >> 7, kl = tid & 127;
            int k = q * 128 + kl;
            float s0 = 0, s1 = 0, s2 = 0, s3 = 0, s4 = 0, s5 = 0;
#pragma unroll
            for (int p = 0; p < 4; p++) {
                const float* e = exg + (size_t)(g * 4 + p) * 6144 + (size_t)(r * 6) * 512 + k;
                s0 += e[0];    s1 += e[512];  s2 += e[1024];
                s3 += e[1536]; s4 += e[2048]; s5 += e[2560];
            }
            float rr = fast_sigmoid(s0 + b_ih[k] + s3 + b_hh[k]);
            float zz = fast_sigmoid(s1 + b_ih[HH + k] + s4 + b_hh[HH + k]);
            float nn = fast_tanh(s2 + b_ih[2 * HH + k] + rr * (s5 + b_hh[2 * HH + k]));
            h_l[r][kl] = (1.f - zz) * nn + zz * h_l[r][kl];
        }
        __syncthreads();

        // ---- W2h partials over own j-quarter (stream = 0.25MB W2 quarter)
        {
            float b0 = 0.f, b1 = 0.f;
            int jqbeg = q * 32 + jh * 16;
#pragma unroll 4
            for (int jj = 0; jj < 16; jj++) {
                int jq = jqbeg + jj;
                int jl4 = (jq - q * 32) * 4;
                float4 h0 = *(const float4*)&h_l[0][jl4];
                float4 h1 = *(const float4*)&h_l[1][jl4];
                float4 w = w2T4[(size_t)jq * HH + k9];
                b0 += h0.x * w.x + h0.y * w.y + h0.z * w.z + h0.w * w.w;
                b1 += h1.x * w.x + h1.y * w.y + h1.z * w.z + h1.w * w.w;
            }
            wp[0][jh][k9] = b0;
            wp[1][jh][k9] = b1;
        }
        __syncthreads();
        {
            int r = tid >> 9, kk = tid & 511;
            exg2[exg2B + tid] = wp[r][0][kk] + wp[r][1][kk];
        }
        gsync(arr, g, blk, tid, 3 * t + 2);
        {
            int r = tid >> 9, kk = tid & 511;
            float s = 0.f;
#pragma unroll
            for (int p = 0; p < 4; p++)
                s += exg2[(size_t)(g * 4 + p) * 1024 + r * 512 + kk];
            w2l[r][kk] = s;
        }
        __syncthreads();

        // ---- score own n-quarter, both rows (stream = 0.25MB W1e quarter)
        {
            int row = wv >> 3;
            int rowAbs = g * 2 + row;
            int nl0 = (wv & 7) * 8;
            float w2r[8];
            {
                const float* p = &w2l[row][lane * 8];
                float4 A = *(const float4*)p;
                float4 B = *(const float4*)(p + 4);
                w2r[0] = A.x; w2r[1] = A.y; w2r[2] = A.z; w2r[3] = A.w;
                w2r[4] = B.x; w2r[5] = B.y; w2r[6] = B.z; w2r[7] = B.w;
            }
            const float* Wb = W1e + ((size_t)rowAbs * NN + q * 64) * HH + lane * 8;
#pragma unroll 2
            for (int i = 0; i < 8; i++) {
                int nl = nl0 + i;
                const float* Wp = Wb + (size_t)nl * HH;
                float4 A0 = *(const float4*)Wp;
                float4 A1 = *(const float4*)(Wp + 4);
                float p = fast_tanh(A0.x + w2r[0]) * vr[0] +
                          fast_tanh(A0.y + w2r[1]) * vr[1] +
                          fast_tanh(A0.z + w2r[2]) * vr[2] +
                          fast_tanh(A0.w + w2r[3]) * vr[3] +
                          fast_tanh(A1.x + w2r[4]) * vr[4] +
                          fast_tanh(A1.y + w2r[5]) * vr[5] +
                          fast_tanh(A1.z + w2r[6]) * vr[6] +
                          fast_tanh(A1.w + w2r[7]) * vr[7];
                p += __shfl_xor(p, 1);
                p += __shfl_xor(p, 2);
                p += __shfl_xor(p, 4);
                p += __shfl_xor(p, 8);
                p += __shfl_xor(p, 16);
                p += __shfl_xor(p, 32);
                if (lane == 0) ul[row][nl] = p;
            }
        }
        __syncthreads();

        // ---- quarter stats: wave0=row0, wave1=row1 (64 lanes = 64 n)
        if (wv < 2) {
            int row = wv;
            int n = q * 64 + lane;
            float val = mask_l[row][n] ? -1.0e9f : ul[row][lane];
            float bv = val; int bi = n;
            for (int off = 32; off > 0; off >>= 1) {
                float ov = __shfl_down(bv, off);
                int oi = __shfl_down(bi, off);
                if (ov > bv || (ov == bv && oi < bi)) { bv = ov; bi = oi; }
            }
            float m = __shfl(bv, 0);
            int mi = __shfl(bi, 0);
            float d = val - m;
            float e = __expf(d);
            float ed = e * d;
            for (int off = 32; off > 0; off >>= 1) {
                e += __shfl_down(e, off);
                ed += __shfl_down(ed, off);
            }
            if (lane == 0) {
                float4 st = make_float4(m, e, ed, (float)mi);
                *(float4*)&statsX[(size_t)(blk * 2 + row) * 16] = st;
            }
        }
        gsync(arr, g, blk, tid, 3 * t + 3);

        // ---- final combine (redundant in all 4 blocks)
        if (tid < 2) {
            int r = tid;
            float m = -3.0e38f; int idx = 1 << 30;
            float ms[4], Ss[4], Es[4]; int is[4];
#pragma unroll
            for (int p = 0; p < 4; p++) {
                float4 st = *(const float4*)&statsX[(size_t)((g * 4 + p) * 2 + r) * 16];
                ms[p] = st.x; Ss[p] = st.y; Es[p] = st.z; is[p] = (int)st.w;
            }
#pragma unroll
            for (int p = 0; p < 4; p++) {
                if (ms[p] > m) { m = ms[p]; idx = is[p]; }
            }
            float S = 0.f, E = 0.f;
#pragma unroll
            for (int p = 0; p < 4; p++) {
                float c = __expf(ms[p] - m);
                S += Ss[p] * c;
                E += (Es[p] + (ms[p] - m) * Ss[p]) * c;
            }
            s_idx[r] = idx;
            mask_l[r][idx] = 1;
            if (q == 0) {
                int rowAbs = g * 2 + r;
                float inv = 1.0f / S;
                out[rowAbs * T_STEPS + t] = (float)idx;
                out[BB * T_STEPS + rowAbs * T_STEPS + t] = logf(inv + 1e-9f);
                out[2 * BB * T_STEPS + rowAbs * T_STEPS + t] = logf(S) - inv * E;
            }
        }
        __syncthreads();
        // ---- gather next x (own j-quarter)
        if (tid < 256) {
            int r = tid >> 7, jl = tid & 127;
            int rowAbs = g * 2 + r;
            x_l[r][jl] = enc[((size_t)rowAbs * NN + s_idx[r]) * HH + q * 128 + jl];
        }
        __syncthreads();
    }
}

extern "C" void kernel_launch(void* const* d_in, const int* in_sizes, int n_in,
                              void* d_out, int out_size, void* d_ws, size_t ws_size,
                              hipStream_t stream) {
    const float* enc  = (const float*)d_in[0];
    const float* w_ih = (const float*)d_in[1];
    const float* w_hh = (const float*)d_in[2];
    const float* b_ih = (const float*)d_in[3];
    const float* b_hh = (const float*)d_in[4];
    const float* W1   = (const float*)d_in[5];
    const float* W2   = (const float*)d_in[6];
    const float* v    = (const float*)d_in[7];
    float* out = (float*)d_out;

    float* ws = (float*)d_ws;
    float*  W1e    = ws;                                    // 64MB
    float4* gT4    = (float4*)(W1e + (size_t)BB * NN * HH); // 6MB
    float4* w2T4   = gT4 + (size_t)6 * JQ * HH;             // 1MB
    float*  exg    = (float*)(w2T4 + (size_t)JQ * HH);      // 6MB
    float*  exg2   = exg + (size_t)NBLK * 6144;             // 1MB
    float*  statsX = exg2 + (size_t)NBLK * 1024;            // 64KB
    int*    arr    = (int*)(statsX + (size_t)NBLK * 2 * 16);// 16KB

    init_kernel<<<1, 256, 0, stream>>>(arr);
    w1e_gemm<<<dim3((BB * NN) / 64, HH / 64), 256, 0, stream>>>(enc, W1, W1e);
    prep_kernel<<<7 * JQ, 512, 0, stream>>>(w_ih, w_hh, W2, gT4, w2T4);

    void* args[] = {
        (void*)&enc, (void*)&b_ih, (void*)&b_hh, (void*)&gT4, (void*)&w2T4,
        (void*)&v, (void*)&W1e, (void*)&exg, (void*)&exg2, (void*)&statsX,
        (void*)&arr, (void*)&out};
    hipLaunchCooperativeKernel((void*)decode_kernel, dim3(NBLK), dim3(1024),
                               args, 0, stream);
}